// Round 2
// baseline (2356.885 us; speedup 1.0000x reference)
//
#include <hip/hip_runtime.h>
#include <cstddef>
#include <cstdint>

// VQ-VAE segment, chunked low-workspace pipeline.
// B=256 T=512 D=96 H=128 4H=512 L=128 K=1024, NTOK=131072.
// Key identity: decoder input projection = preCB[idx] where
// preCB = codebook @ dec_Wih^T + dec_bih + dec_bhh  (exact).

#define B_ 256
#define T_ 512
#define D_ 96
#define H_ 128
#define G_ 512
#define L_ 128
#define K_ 1024
#define NTOK 131072

__device__ __forceinline__ float fsig(float x) { return 1.0f / (1.0f + __expf(-x)); }
__device__ __forceinline__ float ftanh(float x) { return 1.0f - 2.0f / (1.0f + __expf(2.0f * x)); }

// row offset helper: m -> (m>>lg)*stride + (m & ((1<<lg)-1))*len
__device__ __forceinline__ size_t rowOff(int m, int lg, long stride, int len) {
    return (size_t)(m >> lg) * (size_t)stride + (size_t)(m & ((1 << lg) - 1)) * (size_t)len;
}

__global__ __launch_bounds__(256) void zero_kernel(float* __restrict__ p, int n)
{
    int i = blockIdx.x * 256 + threadIdx.x;
    if (i < n) p[i] = 0.f;
}

// ---------------------------------------------------------------------------
// C[m,n] = dot(Arow(m), W[n]) + b0[n] (+b1[n]).  BM=BN=64, BK=32, block 256.
// A rows / C rows addressed via (lg, stride) chunk mapping.
// ---------------------------------------------------------------------------
__global__ __launch_bounds__(256) void gemm_bias_kernel(
    const float* __restrict__ A, long aStride, int lgA,
    const float* __restrict__ W,
    const float* __restrict__ b0, const float* __restrict__ b1,
    float* __restrict__ C, long cStride, int lgC,
    int N, int K)
{
    __shared__ __align__(16) float As[32][68];
    __shared__ __align__(16) float Bs[32][68];
    const int n_base = blockIdx.x * 64, m_base = blockIdx.y * 64;
    const int tid = threadIdx.x;
    const int tx = tid & 15, ty = tid >> 4;

    float acc[4][4] = {};

    for (int k0 = 0; k0 < K; k0 += 32) {
#pragma unroll
        for (int r = 0; r < 2; ++r) {
            int f4 = tid + r * 256;
            int m = f4 >> 3;
            int kq = (f4 & 7) * 4;
            float4 v = *(const float4*)(A + rowOff(m_base + m, lgA, aStride, K) + (k0 + kq));
            As[kq + 0][m] = v.x; As[kq + 1][m] = v.y; As[kq + 2][m] = v.z; As[kq + 3][m] = v.w;
            float4 wv = make_float4(0.f, 0.f, 0.f, 0.f);
            if (n_base + m < N)
                wv = *(const float4*)(W + (size_t)(n_base + m) * K + (k0 + kq));
            Bs[kq + 0][m] = wv.x; Bs[kq + 1][m] = wv.y; Bs[kq + 2][m] = wv.z; Bs[kq + 3][m] = wv.w;
        }
        __syncthreads();
#pragma unroll
        for (int k = 0; k < 32; ++k) {
            float4 a4 = *(const float4*)&As[k][ty * 4];
            float4 b4 = *(const float4*)&Bs[k][tx * 4];
            float a_[4] = {a4.x, a4.y, a4.z, a4.w};
            float b_[4] = {b4.x, b4.y, b4.z, b4.w};
#pragma unroll
            for (int i = 0; i < 4; ++i)
#pragma unroll
                for (int j = 0; j < 4; ++j)
                    acc[i][j] = fmaf(a_[i], b_[j], acc[i][j]);
        }
        __syncthreads();
    }

#pragma unroll
    for (int i = 0; i < 4; ++i) {
        int m = m_base + ty * 4 + i;
        size_t cro = rowOff(m, lgC, cStride, N);
#pragma unroll
        for (int j = 0; j < 4; ++j) {
            int n = n_base + tx * 4 + j;
            if (n < N) {
                float bias = (b0 ? b0[n] : 0.f) + (b1 ? b1[n] : 0.f);
                C[cro + n] = acc[i][j] + bias;
            }
        }
    }
}

// ---------------------------------------------------------------------------
// LSTM chunk. grid = B (1 block/CU), block = 512 (1 thread per gate row).
// Whh row in 32 float4 VGPRs. Either reads preXc directly (encoder) or
// gathers preCB[idx] (decoder). h/c state carried in hstate/cstate.
// ---------------------------------------------------------------------------
__global__ __launch_bounds__(512) void lstm_kernel(
    const float* __restrict__ preXc,    // [B][Tc][512] or nullptr
    const float* __restrict__ idxBase,  // idxf + t0 (or nullptr)
    const float* __restrict__ preCB,    // [1024][512]
    const float* __restrict__ Whh,      // [512][128]
    float* __restrict__ Hc,             // [B][Tc][128]
    float* __restrict__ hstate,         // [B][128]
    float* __restrict__ cstate,         // [B][128]
    int Tc)
{
    const int b = blockIdx.x;
    const int g = threadIdx.x;

    float4 w[32];
    const float4* wrow = (const float4*)(Whh + (size_t)g * H_);
#pragma unroll
    for (int i = 0; i < 32; ++i) w[i] = wrow[i];

    __shared__ __align__(16) float4 h4s[32];
    __shared__ float c_s[H_];
    __shared__ float gates[G_];

    if (g < H_) {
        ((float*)h4s)[g] = hstate[(size_t)b * H_ + g];
        c_s[g] = cstate[(size_t)b * H_ + g];
    }
    __syncthreads();

    const float* px = preXc ? (preXc + (size_t)b * Tc * G_) : nullptr;
    const float* irow = idxBase ? (idxBase + (size_t)b * T_) : nullptr;
    float* ho = Hc + (size_t)b * Tc * H_;

    float pre;
    if (px) pre = px[g];
    else {
        int k0i = (int)irow[0];
        pre = preCB[(size_t)k0i * G_ + g];
    }

    for (int tl = 0; tl < Tc; ++tl) {
        float pre_next = 0.f;
        if (tl + 1 < Tc) {
            if (px) pre_next = px[(size_t)(tl + 1) * G_ + g];
            else {
                int kn = (int)irow[tl + 1];
                pre_next = preCB[(size_t)kn * G_ + g];
            }
        }
        float a0 = pre, a1 = 0.f, a2 = 0.f, a3 = 0.f;
#pragma unroll
        for (int i = 0; i < 32; i += 4) {
            float4 h0 = h4s[i], h1 = h4s[i + 1], h2 = h4s[i + 2], h3 = h4s[i + 3];
            a0 = fmaf(w[i].x, h0.x, a0);     a0 = fmaf(w[i].y, h0.y, a0);
            a0 = fmaf(w[i].z, h0.z, a0);     a0 = fmaf(w[i].w, h0.w, a0);
            a1 = fmaf(w[i + 1].x, h1.x, a1); a1 = fmaf(w[i + 1].y, h1.y, a1);
            a1 = fmaf(w[i + 1].z, h1.z, a1); a1 = fmaf(w[i + 1].w, h1.w, a1);
            a2 = fmaf(w[i + 2].x, h2.x, a2); a2 = fmaf(w[i + 2].y, h2.y, a2);
            a2 = fmaf(w[i + 2].z, h2.z, a2); a2 = fmaf(w[i + 2].w, h2.w, a2);
            a3 = fmaf(w[i + 3].x, h3.x, a3); a3 = fmaf(w[i + 3].y, h3.y, a3);
            a3 = fmaf(w[i + 3].z, h3.z, a3); a3 = fmaf(w[i + 3].w, h3.w, a3);
        }
        gates[g] = (a0 + a1) + (a2 + a3);
        __syncthreads();
        if (g < H_) {
            float ig = fsig(gates[g]);
            float fg = fsig(gates[g + 128]);
            float gg = ftanh(gates[g + 256]);
            float og = fsig(gates[g + 384]);
            float c = fmaf(fg, c_s[g], ig * gg);
            c_s[g] = c;
            float h = og * ftanh(c);
            ((float*)h4s)[g] = h;
            ho[(size_t)tl * H_ + g] = h;
        }
        __syncthreads();
        pre = pre_next;
    }

    if (g < H_) {
        hstate[(size_t)b * H_ + g] = ((float*)h4s)[g];
        cstate[(size_t)b * H_ + g] = c_s[g];
    }
}

// ---------------------------------------------------------------------------
// mu/logvar GEMMs + z + KL partial, per chunk. grid = B*Tc/64, block 256.
// ---------------------------------------------------------------------------
__global__ __launch_bounds__(256) void mu_logvar_z_kernel(
    const float* __restrict__ Hc,     // [B*Tc,128] contiguous
    const float* __restrict__ Wmu, const float* __restrict__ bmu,
    const float* __restrict__ Wlv, const float* __restrict__ blv,
    const float* __restrict__ epsBase, long epsStride, int lg,
    float* __restrict__ Zc,           // [B*Tc,128]
    float* __restrict__ klpart)       // one slot per block
{
    __shared__ __align__(16) float As[32][68];
    __shared__ __align__(16) float Bmu[32][132];
    __shared__ __align__(16) float Blv[32][132];
    __shared__ float redbuf[8];

    const int m_base = blockIdx.x * 64;
    const int tid = threadIdx.x;
    const int tx = tid & 31, ty = tid >> 5;
    const int n0 = tx * 4;

    float amu[8][4] = {};
    float alv[8][4] = {};

    for (int k0 = 0; k0 < 128; k0 += 32) {
#pragma unroll
        for (int r = 0; r < 2; ++r) {
            int f4 = tid + r * 256;
            int m = f4 >> 3;
            int kq = (f4 & 7) * 4;
            float4 v = *(const float4*)(Hc + (size_t)(m_base + m) * H_ + (k0 + kq));
            As[kq + 0][m] = v.x; As[kq + 1][m] = v.y; As[kq + 2][m] = v.z; As[kq + 3][m] = v.w;
        }
#pragma unroll
        for (int r = 0; r < 4; ++r) {
            int f4 = tid + r * 256;
            int n = f4 >> 3;
            int kq = (f4 & 7) * 4;
            float4 v = *(const float4*)(Wmu + (size_t)n * H_ + (k0 + kq));
            Bmu[kq + 0][n] = v.x; Bmu[kq + 1][n] = v.y; Bmu[kq + 2][n] = v.z; Bmu[kq + 3][n] = v.w;
            float4 u = *(const float4*)(Wlv + (size_t)n * H_ + (k0 + kq));
            Blv[kq + 0][n] = u.x; Blv[kq + 1][n] = u.y; Blv[kq + 2][n] = u.z; Blv[kq + 3][n] = u.w;
        }
        __syncthreads();
#pragma unroll 4
        for (int k = 0; k < 32; ++k) {
            float4 a0 = *(const float4*)&As[k][ty * 8];
            float4 a1 = *(const float4*)&As[k][ty * 8 + 4];
            float4 bm4 = *(const float4*)&Bmu[k][n0];
            float4 bl4 = *(const float4*)&Blv[k][n0];
            float a_[8] = {a0.x, a0.y, a0.z, a0.w, a1.x, a1.y, a1.z, a1.w};
            float bm_[4] = {bm4.x, bm4.y, bm4.z, bm4.w};
            float bl_[4] = {bl4.x, bl4.y, bl4.z, bl4.w};
#pragma unroll
            for (int i = 0; i < 8; ++i)
#pragma unroll
                for (int j = 0; j < 4; ++j) {
                    amu[i][j] = fmaf(a_[i], bm_[j], amu[i][j]);
                    alv[i][j] = fmaf(a_[i], bl_[j], alv[i][j]);
                }
        }
        __syncthreads();
    }

    float4 bmu4 = *(const float4*)(bmu + n0);
    float4 blv4 = *(const float4*)(blv + n0);
    float bm_[4] = {bmu4.x, bmu4.y, bmu4.z, bmu4.w};
    float bl_[4] = {blv4.x, blv4.y, blv4.z, blv4.w};

    float kls = 0.f;
#pragma unroll
    for (int i = 0; i < 8; ++i) {
        int row = m_base + ty * 8 + i;
        float4 e4 = *(const float4*)(epsBase + rowOff(row, lg, epsStride, L_) + n0);
        float e_[4] = {e4.x, e4.y, e4.z, e4.w};
        float z_[4];
#pragma unroll
        for (int j = 0; j < 4; ++j) {
            float mu = amu[i][j] + bm_[j];
            float lv = alv[i][j] + bl_[j];
            z_[j] = fmaf(e_[j], __expf(0.5f * lv), mu);
            kls += 1.0f + lv - mu * mu - __expf(lv);
        }
        *(float4*)(Zc + (size_t)row * L_ + n0) = make_float4(z_[0], z_[1], z_[2], z_[3]);
    }

#pragma unroll
    for (int o = 32; o > 0; o >>= 1) kls += __shfl_down(kls, o);
    int w = tid >> 6, l = tid & 63;
    if (l == 0) redbuf[w] = kls;
    __syncthreads();
    if (tid == 0)
        klpart[blockIdx.x] = redbuf[0] + redbuf[1] + redbuf[2] + redbuf[3];
}

// ---------------------------------------------------------------------------
// Codebook squared norms. grid=4, block=256.
// ---------------------------------------------------------------------------
__global__ __launch_bounds__(256) void cc_kernel(const float* __restrict__ CB, float* __restrict__ cc)
{
    int k = blockIdx.x * 256 + threadIdx.x;
    const float4* r = (const float4*)(CB + (size_t)k * L_);
    float s = 0.f;
#pragma unroll
    for (int i = 0; i < 32; ++i) {
        float4 v = r[i];
        s += v.x * v.x + v.y * v.y + v.z * v.z + v.w * v.w;
    }
    cc[k] = s;
}

// ---------------------------------------------------------------------------
// VQ per chunk: distances + argmin + idx write + SSE partial.
// grid = B*Tc/64, block = 256.
// ---------------------------------------------------------------------------
__global__ __launch_bounds__(256) void vq_kernel(
    const float* __restrict__ Zc,      // [B*Tc,128]
    const float* __restrict__ CB,      // [1024,128]
    const float* __restrict__ cc,      // [1024]
    float* __restrict__ idxBase,       // idxf + t0, strided by (lg, T_)
    int lg,
    float* __restrict__ ssepart)       // one slot per block
{
    __shared__ __align__(16) float Zs[128][68];
    __shared__ __align__(16) float Cs[128][68];
    __shared__ float zz_s[64];
    __shared__ float dred[64][16];
    __shared__ int kred[64][16];
    __shared__ int kbest_s[64];
    __shared__ float redbuf[8];

    const int m_base = blockIdx.x * 64;
    const int tid = threadIdx.x;
    const int tx = tid & 15, ty = tid >> 4;

#pragma unroll
    for (int c = 0; c < 4; ++c) {
#pragma unroll
        for (int r = 0; r < 2; ++r) {
            int f4 = tid + r * 256;
            int m = f4 >> 3;
            int kq = (f4 & 7) * 4;
            int k = c * 32 + kq;
            float4 v = *(const float4*)(Zc + (size_t)(m_base + m) * L_ + k);
            Zs[k + 0][m] = v.x; Zs[k + 1][m] = v.y; Zs[k + 2][m] = v.z; Zs[k + 3][m] = v.w;
        }
    }
    __syncthreads();
    if (tid < 64) {
        float s = 0.f;
        for (int k = 0; k < 128; ++k) { float zv = Zs[k][tid]; s = fmaf(zv, zv, s); }
        zz_s[tid] = s;
    }

    float dmin[4] = {3.4e38f, 3.4e38f, 3.4e38f, 3.4e38f};
    int kmin[4] = {0, 0, 0, 0};

    for (int nt = 0; nt < 16; ++nt) {
        __syncthreads();
#pragma unroll
        for (int c = 0; c < 4; ++c) {
#pragma unroll
            for (int r = 0; r < 2; ++r) {
                int f4 = tid + r * 256;
                int n = f4 >> 3;
                int kq = (f4 & 7) * 4;
                int k = c * 32 + kq;
                float4 v = *(const float4*)(CB + (size_t)(nt * 64 + n) * L_ + k);
                Cs[k + 0][n] = v.x; Cs[k + 1][n] = v.y; Cs[k + 2][n] = v.z; Cs[k + 3][n] = v.w;
            }
        }
        __syncthreads();

        float acc[4][4] = {};
#pragma unroll 4
        for (int k = 0; k < 128; ++k) {
            float4 a4 = *(const float4*)&Zs[k][ty * 4];
            float4 b4 = *(const float4*)&Cs[k][tx * 4];
            float a_[4] = {a4.x, a4.y, a4.z, a4.w};
            float b_[4] = {b4.x, b4.y, b4.z, b4.w};
#pragma unroll
            for (int i = 0; i < 4; ++i)
#pragma unroll
                for (int j = 0; j < 4; ++j)
                    acc[i][j] = fmaf(a_[i], b_[j], acc[i][j]);
        }

#pragma unroll
        for (int i = 0; i < 4; ++i) {
            float zzv = zz_s[ty * 4 + i];
#pragma unroll
            for (int j = 0; j < 4; ++j) {
                int code = nt * 64 + tx * 4 + j;
                float d = (zzv + cc[code]) - 2.0f * acc[i][j];
                if (d < dmin[i]) { dmin[i] = d; kmin[i] = code; }
            }
        }
    }

#pragma unroll
    for (int i = 0; i < 4; ++i) {
        dred[ty * 4 + i][tx] = dmin[i];
        kred[ty * 4 + i][tx] = kmin[i];
    }
    __syncthreads();
    if (tid < 64) {
        int r = tid;
        float bd = dred[r][0];
        int bk = kred[r][0];
#pragma unroll
        for (int t = 1; t < 16; ++t) {
            float d = dred[r][t];
            if (d < bd) { bd = d; bk = kred[r][t]; }
        }
        kbest_s[r] = bk;
        int rg = m_base + r;
        idxBase[(size_t)(rg >> lg) * T_ + (rg & ((1 << lg) - 1))] = (float)bk;
    }
    __syncthreads();

    float sse = 0.f;
#pragma unroll
    for (int r = 0; r < 8; ++r) {
        int f4 = tid + r * 256;
        int row = f4 >> 5;
        int cq = (f4 & 31) * 4;
        int kb = kbest_s[row];
        float4 qv = *(const float4*)(CB + (size_t)kb * L_ + cq);
        float4 zv = *(const float4*)(Zc + (size_t)(m_base + row) * L_ + cq);
        float dx = qv.x - zv.x, dy = qv.y - zv.y, dz = qv.z - zv.z, dw = qv.w - zv.w;
        sse += dx * dx + dy * dy + dz * dz + dw * dw;
    }
#pragma unroll
    for (int o = 32; o > 0; o >>= 1) sse += __shfl_down(sse, o);
    int w = tid >> 6, l = tid & 63;
    if (l == 0) redbuf[w] = sse;
    __syncthreads();
    if (tid == 0)
        ssepart[blockIdx.x] = redbuf[0] + redbuf[1] + redbuf[2] + redbuf[3];
}

// ---------------------------------------------------------------------------
__global__ __launch_bounds__(256) void finalize_kernel(
    const float* __restrict__ klpart, const float* __restrict__ ssepart,
    float* __restrict__ loss_out)
{
    float skl = 0.f, ssse = 0.f;
    for (int i = threadIdx.x; i < 2048; i += 256) { skl += klpart[i]; ssse += ssepart[i]; }
#pragma unroll
    for (int o = 32; o > 0; o >>= 1) { skl += __shfl_down(skl, o); ssse += __shfl_down(ssse, o); }
    __shared__ float s1[4], s2[4];
    int w = threadIdx.x >> 6, l = threadIdx.x & 63;
    if (l == 0) { s1[w] = skl; s2[w] = ssse; }
    __syncthreads();
    if (threadIdx.x == 0) {
        float K = s1[0] + s1[1] + s1[2] + s1[3];
        float S = s2[0] + s2[1] + s2[2] + s2[3];
        loss_out[0] = 1.25f * (S / 16777216.0f) - 0.5f * K;
    }
}

// ---------------------------------------------------------------------------
extern "C" void kernel_launch(void* const* d_in, const int* in_sizes, int n_in,
                              void* d_out, int out_size, void* d_ws, size_t ws_size,
                              hipStream_t stream)
{
    const float* traj     = (const float*)d_in[0];
    const float* eps      = (const float*)d_in[1];
    const float* enc_Wih  = (const float*)d_in[2];
    const float* enc_Whh  = (const float*)d_in[3];
    const float* enc_bih  = (const float*)d_in[4];
    const float* enc_bhh  = (const float*)d_in[5];
    const float* fc_mu_W  = (const float*)d_in[6];
    const float* fc_mu_b  = (const float*)d_in[7];
    const float* fc_lv_W  = (const float*)d_in[8];
    const float* fc_lv_b  = (const float*)d_in[9];
    const float* codebook = (const float*)d_in[10];
    const float* dec_Wih  = (const float*)d_in[11];
    const float* dec_Whh  = (const float*)d_in[12];
    const float* dec_bih  = (const float*)d_in[13];
    const float* dec_bhh  = (const float*)d_in[14];
    const float* dec_fc_W = (const float*)d_in[15];
    const float* dec_fc_b = (const float*)d_in[16];

    float* out   = (float*)d_out;
    float* recon = out;                 // [256,512,96]
    float* loss  = out + 12582912;      // scalar
    float* idxf  = out + 12582913;      // [131072]

    // pick largest chunk Tc that fits in ws_size
    int Tc = 256;
    while (Tc > 16) {
        size_t bytes = 4ull * ((size_t)B_ * Tc * (G_ + H_ + L_) + 524288 + 1024 + 65536 + 4096);
        if (bytes <= ws_size) break;
        Tc >>= 1;
    }
    const int lg = __builtin_ctz(Tc);
    const int nchunks = T_ / Tc;
    const int blocksPerChunk = (B_ * Tc) / 64;

    float* ws = (float*)d_ws;
    float* preXc   = ws;                              // B*Tc*512
    float* Hc      = preXc + (size_t)B_ * Tc * G_;    // B*Tc*128
    float* Zc      = Hc + (size_t)B_ * Tc * H_;       // B*Tc*128
    float* preCB   = Zc + (size_t)B_ * Tc * L_;       // 524288
    float* ccbuf   = preCB + (size_t)K_ * G_;         // 1024
    float* hstate  = ccbuf + 1024;                    // 32768
    float* cstate  = hstate + (size_t)B_ * H_;        // 32768
    float* klpart  = cstate + (size_t)B_ * H_;        // 2048
    float* ssepart = klpart + 2048;                   // 2048

    // precompute: preCB = codebook @ dec_Wih^T + dec_bih + dec_bhh  [1024,512]
    gemm_bias_kernel<<<dim3(8, 16), 256, 0, stream>>>(
        codebook, 0, 30, dec_Wih, dec_bih, dec_bhh, preCB, 0, 30, G_, L_);
    // codebook norms
    cc_kernel<<<4, 256, 0, stream>>>(codebook, ccbuf);
    // zero enc h/c state
    zero_kernel<<<256, 256, 0, stream>>>(hstate, 2 * B_ * H_);

    // ---- encoder + VQ, chunked over T ----
    for (int ci = 0; ci < nchunks; ++ci) {
        const int t0 = ci * Tc;
        gemm_bias_kernel<<<dim3(8, blocksPerChunk), 256, 0, stream>>>(
            traj + (size_t)t0 * D_, (long)T_ * D_, lg,
            enc_Wih, enc_bih, enc_bhh,
            preXc, 0, 30, G_, D_);
        lstm_kernel<<<B_, 512, 0, stream>>>(
            preXc, nullptr, nullptr, enc_Whh, Hc, hstate, cstate, Tc);
        mu_logvar_z_kernel<<<blocksPerChunk, 256, 0, stream>>>(
            Hc, fc_mu_W, fc_mu_b, fc_lv_W, fc_lv_b,
            eps + (size_t)t0 * L_, (long)T_ * L_, lg,
            Zc, klpart + (size_t)ci * blocksPerChunk);
        vq_kernel<<<blocksPerChunk, 256, 0, stream>>>(
            Zc, codebook, ccbuf, idxf + t0, lg,
            ssepart + (size_t)ci * blocksPerChunk);
    }

    // zero dec h/c state
    zero_kernel<<<256, 256, 0, stream>>>(hstate, 2 * B_ * H_);

    // ---- decoder + recon, chunked over T ----
    for (int ci = 0; ci < nchunks; ++ci) {
        const int t0 = ci * Tc;
        lstm_kernel<<<B_, 512, 0, stream>>>(
            nullptr, idxf + t0, preCB, dec_Whh, Hc, hstate, cstate, Tc);
        gemm_bias_kernel<<<dim3(2, blocksPerChunk), 256, 0, stream>>>(
            Hc, 0, 30, dec_fc_W, dec_fc_b, nullptr,
            recon + (size_t)t0 * D_, (long)T_ * D_, lg, D_, H_);
    }

    // ---- final loss ----
    finalize_kernel<<<1, 256, 0, stream>>>(klpart, ssepart, loss);
}